// Round 3
// baseline (390.776 us; speedup 1.0000x reference)
//
#include <hip/hip_runtime.h>

// W8A8 quantized linear on gfx950.
// R3: single fused quant kernel; GEMM switched to mfma_i32_32x32x32_i8
// (half the ds_read bytes per op vs 16x16x64), BK=128, XOR-swizzled LDS.

using v4i  = __attribute__((ext_vector_type(4))) int;
using v16i = __attribute__((ext_vector_type(16))) int;

typedef const __attribute__((address_space(1))) signed char gc_t;
typedef __attribute__((address_space(3))) signed char lc_t;

constexpr int BM = 128;
constexpr int BN = 128;
constexpr int BK = 128;   // int8 elements per K-tile (128 B rows)

// ---- quantization ---------------------------------------------------------

__device__ __forceinline__ int quant4(const float4 f, float s) {
    // clamp(x/s, -128, 127) then trunc-toward-zero, pack 4 int8 into one dword
    int a = (int)fminf(fmaxf(f.x / s, -128.0f), 127.0f);
    int b = (int)fminf(fmaxf(f.y / s, -128.0f), 127.0f);
    int c = (int)fminf(fmaxf(f.z / s, -128.0f), 127.0f);
    int d = (int)fminf(fmaxf(f.w / s, -128.0f), 127.0f);
    return (a & 0xff) | ((b & 0xff) << 8) | ((c & 0xff) << 16) | ((d & 0xff) << 24);
}

__global__ void quant_fused_kernel(const float4* __restrict__ x,
                                   const float4* __restrict__ w,
                                   const float* __restrict__ scale,
                                   int* __restrict__ outx,
                                   int* __restrict__ outw,
                                   int nx4, int nw4) {
    int i = blockIdx.x * blockDim.x + threadIdx.x;
    if (i < nx4) {
        outx[i] = quant4(x[i], scale[0]);          // 16B/lane load, 4B/lane store
    } else {
        int j = i - nx4;
        if (j < nw4) {
            float4 f = w[j];                       // weights already exact ints
            outw[j] = ((int)f.x & 0xff) | (((int)f.y & 0xff) << 8) |
                      (((int)f.z & 0xff) << 16) | (((int)f.w & 0xff) << 24);
        }
    }
}

// ---- int8 GEMM: C[m][n] = sum_k A[m][k]*W[n][k], dequant + bias -----------
//
// LDS swizzle: global_load_lds forces LDS dest = base + lane*16, so we swizzle
// the GLOBAL source. LDS slot (row r, 16B-chunk c) holds global chunk c^(r&7).
// Staging rows/inst = 8, so r&7 == lane>>3 -> source chunk = (lane&7)^(lane>>3).
// Fragment reads XOR the chunk back; bank = chunk*4 mod 32 (row term = 128B
// stride cancels mod 32), 8 distinct chunks per 8 rows -> conflict-free.

__global__ __launch_bounds__(256, 4) void gemm_i8_kernel(
    const signed char* __restrict__ Aq,   // [M][K] int8
    const signed char* __restrict__ Wq,   // [N][K] int8
    const float* __restrict__ wscale,     // [N]
    const float* __restrict__ iscale,     // [1]
    const float* __restrict__ bias,       // [N]
    float* __restrict__ C,                // [M][N]
    int M, int N, int K)
{
    __shared__ signed char As[BM * BK];   // 16 KB
    __shared__ signed char Bs[BN * BK];   // 16 KB

    const int tid  = threadIdx.x;
    const int wave = tid >> 6;          // 0..3
    const int lane = tid & 63;
    const int wm   = (wave >> 1) * 64;  // wave's 64x64 patch of the 128x128 tile
    const int wn   = (wave & 1) * 64;

    const int m0 = blockIdx.y * BM;
    const int n0 = blockIdx.x * BN;

    // staging lane mapping (per inst: 8 rows x 128 B)
    const int srow   = lane >> 3;             // 0..7
    const int gchunk = (lane & 7) ^ srow;     // swizzled global source chunk

    // 32x32x32 i8 fragment addressing: row/col = lane&31, k-half = lane>>5
    // (16 consecutive k-bytes per lane; intra-lane k order is self-canceling
    // between A and B)
    const int fr = lane & 31;
    const int kh = lane >> 5;
    // swizzled LDS byte offsets for k-step s (global chunk = s*2 + kh)
    int coff[4];
#pragma unroll
    for (int s = 0; s < 4; ++s) coff[s] = ((s * 2 + kh) ^ (fr & 7)) * 16;

    v16i acc[2][2];
#pragma unroll
    for (int i = 0; i < 2; ++i)
#pragma unroll
        for (int j = 0; j < 2; ++j)
#pragma unroll
            for (int r = 0; r < 16; ++r) acc[i][j][r] = 0;

    const size_t Kz = (size_t)K;
    const signed char* pA = Aq + (size_t)(m0 + wave * 32 + srow) * Kz + gchunk * 16;
    const signed char* pB = Wq + (size_t)(n0 + wave * 32 + srow) * Kz + gchunk * 16;
    lc_t* lA = (lc_t*)(As + (wave * 32) * BK);
    lc_t* lB = (lc_t*)(Bs + (wave * 32) * BK);

    for (int k0 = 0; k0 < K; k0 += BK) {
        // ---- stage A and B tiles: 4 insts each per wave (8 rows/inst) ----
#pragma unroll
        for (int c = 0; c < 4; ++c) {
            __builtin_amdgcn_global_load_lds((gc_t*)(pA + (size_t)(c * 8) * Kz),
                                             lA + c * 8 * BK, 16, 0, 0);
            __builtin_amdgcn_global_load_lds((gc_t*)(pB + (size_t)(c * 8) * Kz),
                                             lB + c * 8 * BK, 16, 0, 0);
        }
        pA += BK;
        pB += BK;
        __syncthreads();

        // ---- 4 k-steps of 32; per step: 4 ds_read_b128 + 4 MFMA(32x32x32) ----
#pragma unroll
        for (int s = 0; s < 4; ++s) {
            v4i af[2], bf[2];
#pragma unroll
            for (int t = 0; t < 2; ++t)
                af[t] = *(const v4i*)(As + (wm + t * 32 + fr) * BK + coff[s]);
#pragma unroll
            for (int t = 0; t < 2; ++t)
                bf[t] = *(const v4i*)(Bs + (wn + t * 32 + fr) * BK + coff[s]);
#pragma unroll
            for (int mt = 0; mt < 2; ++mt)
#pragma unroll
                for (int nt = 0; nt < 2; ++nt)
                    acc[mt][nt] = __builtin_amdgcn_mfma_i32_32x32x32_i8(
                        af[mt], bf[nt], acc[mt][nt], 0, 0, 0);
        }
        __syncthreads();
    }

    // ---- epilogue: dequant + bias ----
    // 32x32 C/D layout (HW-verified, dtype-independent):
    //   col = lane&31, row = (reg&3) + 8*(reg>>2) + 4*(lane>>5)
    const float is = iscale[0];
#pragma unroll
    for (int nt = 0; nt < 2; ++nt) {
        const int col = n0 + wn + nt * 32 + fr;
        const float sc = wscale[col] * is;
        const float bv = bias[col];
#pragma unroll
        for (int mt = 0; mt < 2; ++mt) {
            const int rbase = m0 + wm + mt * 32 + 4 * kh;
#pragma unroll
            for (int r = 0; r < 16; ++r) {
                const int row = rbase + (r & 3) + 8 * (r >> 2);
                C[(size_t)row * N + col] = (float)acc[mt][nt][r] * sc + bv;
            }
        }
    }
}

// ---- launch ---------------------------------------------------------------

extern "C" void kernel_launch(void* const* d_in, const int* in_sizes, int n_in,
                              void* d_out, int out_size, void* d_ws, size_t ws_size,
                              hipStream_t stream) {
    const float* x  = (const float*)d_in[0];   // [B,S,IN] fp32
    const float* qw = (const float*)d_in[1];   // [OUT,IN] fp32 (int8 values)
    const float* ws = (const float*)d_in[2];   // [OUT,1]
    const float* is = (const float*)d_in[3];   // [1]
    const float* bs = (const float*)d_in[4];   // [OUT]
    float* out = (float*)d_out;

    const int nx = in_sizes[0];   // M*K
    const int nw = in_sizes[1];   // N*K
    const int N  = in_sizes[4];   // 4096
    const int K  = nw / N;        // 4096
    const int M  = nx / K;        // 8192

    signed char* xq = (signed char*)d_ws;
    signed char* wq = (signed char*)d_ws + (size_t)nx;

    const int nx4 = nx / 4, nw4 = nw / 4;
    const int qblocks = (nx4 + nw4 + 255) / 256;
    quant_fused_kernel<<<qblocks, 256, 0, stream>>>(
        (const float4*)x, (const float4*)qw, is, (int*)xq, (int*)wq, nx4, nw4);

    dim3 grid(N / BN, M / BM);
    gemm_i8_kernel<<<grid, 256, 0, stream>>>(xq, wq, ws, is, bs, out, M, N, K);
}